// Round 1
// baseline (294.379 us; speedup 1.0000x reference)
//
#include <hip/hip_runtime.h>

#define D_MODEL 1024
#define NHEAD 16
#define HD 64
#define BATCH 2
#define SEQ 2048

typedef unsigned short u16;
typedef __bf16 bf16x8 __attribute__((ext_vector_type(8)));
typedef unsigned short u16x8 __attribute__((ext_vector_type(8)));
typedef float f32x4 __attribute__((ext_vector_type(4)));

// fp32 -> bf16 round-to-nearest-even (inputs are finite; no NaN path needed)
static __device__ __forceinline__ u16 f2bf(float f) {
    union { float f; unsigned u; } v; v.f = f;
    unsigned u = v.u;
    u += 0x7fffu + ((u >> 16) & 1u);
    return (u16)(u >> 16);
}

// async global->LDS, 16B per lane; lds base must be wave-uniform (lane*16 auto-added)
static __device__ __forceinline__ void gld_lds16(const void* g, void* l) {
    __builtin_amdgcn_global_load_lds(
        (const __attribute__((address_space(1))) void*)g,
        (__attribute__((address_space(3))) void*)l, 16, 0, 0);
}

// ---------------- pass 0a: x fp32 -> bf16 ----------------
__global__ __launch_bounds__(256) void k_convert_x(const float* __restrict__ x,
                                                   u16* __restrict__ xb) {
    int i = blockIdx.x * 256 + threadIdx.x;     // one float4 per thread
    float4 v = ((const float4*)x)[i];
    ushort4 o = make_ushort4(f2bf(v.x), f2bf(v.y), f2bf(v.z), f2bf(v.w));
    ((ushort4*)xb)[i] = o;
}

// ---------------- pass 0b: W fp32 [k][n] -> bf16 transposed Wt[n][k] ----------------
__global__ __launch_bounds__(256) void k_convert_wt(const float* __restrict__ wq,
                                                    const float* __restrict__ wk,
                                                    const float* __restrict__ wv,
                                                    const float* __restrict__ wo,
                                                    u16* __restrict__ wt) {
    __shared__ u16 t[32][33];
    const float* W = blockIdx.z == 0 ? wq : blockIdx.z == 1 ? wk
                   : blockIdx.z == 2 ? wv : wo;
    u16* dst = wt + (size_t)blockIdx.z * (D_MODEL * D_MODEL);
    int tx = threadIdx.x & 31, ty = threadIdx.x >> 5;   // ty 0..7
    int n0 = blockIdx.x * 32, k0 = blockIdx.y * 32;
#pragma unroll
    for (int i = 0; i < 4; i++)
        t[ty + i * 8][tx] = f2bf(W[(size_t)(k0 + ty + i * 8) * D_MODEL + n0 + tx]);
    __syncthreads();
#pragma unroll
    for (int i = 0; i < 4; i++)
        dst[(size_t)(n0 + ty + i * 8) * D_MODEL + k0 + tx] = t[tx][ty + i * 8];
}

// ---------------- GEMM: C = A(bf16 MxK) @ Wt^T(bf16, stored [n][k]) + bias ----------------
// mode 0: out bf16, head-split [B,H,S,64], scale folded (Q gets 0.125*log2e)
// mode 1: out fp32 flat [M,N]
__global__ __launch_bounds__(256) void k_gemm(const u16* __restrict__ A,
                                              const u16* __restrict__ WtBase,
                                              const float* __restrict__ b0,
                                              const float* __restrict__ b1,
                                              const float* __restrict__ b2,
                                              u16* __restrict__ oq, u16* __restrict__ ok,
                                              u16* __restrict__ ov,
                                              float* __restrict__ outf, int mode) {
    __shared__ u16 lA[128 * 32];
    __shared__ u16 lB[128 * 32];
    int tid = threadIdx.x, w = tid >> 6, l = tid & 63, lr = l & 15, lq = l >> 4;
    int z = blockIdx.z;
    const u16* Wt = WtBase + (size_t)z * (D_MODEL * D_MODEL);
    const float* bias = (mode == 1) ? b0 : (z == 0 ? b0 : z == 1 ? b1 : b2);
    float scale = (mode == 0 && z == 0) ? (0.125f * 1.44269504088896340736f) : 1.0f;
    int m0 = blockIdx.y * 128, n0 = blockIdx.x * 128;
    int wm = (w >> 1) * 64, wn = (w & 1) * 64;
    f32x4 acc[4][4];
#pragma unroll
    for (int mi = 0; mi < 4; mi++)
#pragma unroll
        for (int ni = 0; ni < 4; ni++) acc[mi][ni] = (f32x4){0.f, 0.f, 0.f, 0.f};

    int ra = tid >> 2, ca = (tid & 3) * 8;
    for (int kk = 0; kk < D_MODEL; kk += 32) {
        gld_lds16(A + (size_t)(m0 + ra) * D_MODEL + kk + ca, &lA[w * 512]);
        gld_lds16(A + (size_t)(m0 + 64 + ra) * D_MODEL + kk + ca, &lA[2048 + w * 512]);
        gld_lds16(Wt + (size_t)(n0 + ra) * D_MODEL + kk + ca, &lB[w * 512]);
        gld_lds16(Wt + (size_t)(n0 + 64 + ra) * D_MODEL + kk + ca, &lB[2048 + w * 512]);
        __syncthreads();
        bf16x8 af[4], bf[4];
#pragma unroll
        for (int mi = 0; mi < 4; mi++)
            af[mi] = *(const bf16x8*)&lA[(wm + mi * 16 + lr) * 32 + lq * 8];
#pragma unroll
        for (int ni = 0; ni < 4; ni++)
            bf[ni] = *(const bf16x8*)&lB[(wn + ni * 16 + lr) * 32 + lq * 8];
#pragma unroll
        for (int mi = 0; mi < 4; mi++)
#pragma unroll
            for (int ni = 0; ni < 4; ni++)
                acc[mi][ni] = __builtin_amdgcn_mfma_f32_16x16x32_bf16(
                    af[mi], bf[ni], acc[mi][ni], 0, 0, 0);
        __syncthreads();
    }
    // epilogue: C/D layout col=lane&15, row=(lane>>4)*4+reg
#pragma unroll
    for (int mi = 0; mi < 4; mi++) {
#pragma unroll
        for (int ni = 0; ni < 4; ni++) {
            int col = n0 + wn + ni * 16 + lr;
            float bval = bias[col];
#pragma unroll
            for (int r = 0; r < 4; r++) {
                int row = m0 + wm + mi * 16 + lq * 4 + r;
                float val = (acc[mi][ni][r] + bval) * scale;
                if (mode == 0) {
                    u16* op = z == 0 ? oq : z == 1 ? ok : ov;
                    int b = row >> 11, s = row & 2047, h = col >> 6, d = col & 63;
                    op[(((size_t)(b * NHEAD + h)) * SEQ + s) * HD + d] = f2bf(val);
                } else {
                    outf[(size_t)row * D_MODEL + col] = val;
                }
            }
        }
    }
}

// ---------------- flash attention: per (b,h), 128 q-rows per block ----------------
// Q pre-scaled by 0.125*log2e -> softmax in exp2 domain.
__global__ __launch_bounds__(256) void k_attn(const u16* __restrict__ Q,
                                              const u16* __restrict__ Kw,
                                              const u16* __restrict__ V,
                                              u16* __restrict__ AO) {
    __shared__ u16 lds[32768];          // 64 KB
    u16* lK = lds;                      // [128][64]
    u16* lVt = lds + 8192;              // [64][128] (V transposed)
    int tid = threadIdx.x, w = tid >> 6, l = tid & 63, lr = l & 15, lq = l >> 4;
    u16* lP = lds + 16384 + w * 4096;   // wave-private [32][128]
    int bh = blockIdx.y, q0 = blockIdx.x * 128;
    const u16* Qb = Q + (size_t)bh * SEQ * HD;
    const u16* Kb = Kw + (size_t)bh * SEQ * HD;
    const u16* Vb = V + (size_t)bh * SEQ * HD;

    bf16x8 qf[2][2];
#pragma unroll
    for (int ti = 0; ti < 2; ti++)
#pragma unroll
        for (int kc = 0; kc < 2; kc++)
            qf[ti][kc] = *(const bf16x8*)&Qb[(size_t)(q0 + w * 32 + ti * 16 + lr) * HD +
                                             kc * 32 + lq * 8];
    f32x4 o[2][4];
    float mrow[2][4], lrow[2][4];
#pragma unroll
    for (int ti = 0; ti < 2; ti++)
#pragma unroll
        for (int r = 0; r < 4; r++) { mrow[ti][r] = -3.0e38f; lrow[ti][r] = 0.f; }
#pragma unroll
    for (int ti = 0; ti < 2; ti++)
#pragma unroll
        for (int di = 0; di < 4; di++) o[ti][di] = (f32x4){0.f, 0.f, 0.f, 0.f};

    int vr = tid & 127, vh = tid >> 7;
    for (int j0 = 0; j0 < SEQ; j0 += 128) {
        // stage K tile (contiguous 16KB) via async DMA
        const u16* Kt = Kb + (size_t)j0 * HD;
#pragma unroll
        for (int c = 0; c < 4; c++)
            gld_lds16(Kt + (size_t)(c * 256 + tid) * 8, &lK[(c * 256 + w * 64) * 8]);
        // stage V transposed: [64][128]
        const u16* Vtg = Vb + (size_t)j0 * HD;
        u16x8 vv[4];
#pragma unroll
        for (int i = 0; i < 4; i++)
            vv[i] = *(const u16x8*)&Vtg[(size_t)vr * HD + vh * 32 + i * 8];
#pragma unroll
        for (int i = 0; i < 4; i++)
#pragma unroll
            for (int jj = 0; jj < 8; jj++)
                lVt[(vh * 32 + i * 8 + jj) * 128 + vr] = vv[i][jj];
        __syncthreads();

        // scores S = Q K^T (already in log2 units)
        f32x4 s[2][8];
#pragma unroll
        for (int ti = 0; ti < 2; ti++)
#pragma unroll
            for (int tj = 0; tj < 8; tj++) s[ti][tj] = (f32x4){0.f, 0.f, 0.f, 0.f};
#pragma unroll
        for (int tj = 0; tj < 8; tj++) {
            bf16x8 kf0 = *(const bf16x8*)&lK[(tj * 16 + lr) * 64 + lq * 8];
            bf16x8 kf1 = *(const bf16x8*)&lK[(tj * 16 + lr) * 64 + 32 + lq * 8];
#pragma unroll
            for (int ti = 0; ti < 2; ti++) {
                s[ti][tj] = __builtin_amdgcn_mfma_f32_16x16x32_bf16(qf[ti][0], kf0,
                                                                    s[ti][tj], 0, 0, 0);
                s[ti][tj] = __builtin_amdgcn_mfma_f32_16x16x32_bf16(qf[ti][1], kf1,
                                                                    s[ti][tj], 0, 0, 0);
            }
        }
        // online softmax (rows: ti*16 + lq*4 + r; cols across tj and 16-lane group)
#pragma unroll
        for (int ti = 0; ti < 2; ti++) {
#pragma unroll
            for (int r = 0; r < 4; r++) {
                float mx = s[ti][0][r];
#pragma unroll
                for (int tj = 1; tj < 8; tj++) mx = fmaxf(mx, s[ti][tj][r]);
#pragma unroll
                for (int off = 1; off < 16; off <<= 1)
                    mx = fmaxf(mx, __shfl_xor(mx, off, 64));
                float mnew = fmaxf(mrow[ti][r], mx);
                float alpha = exp2f(mrow[ti][r] - mnew);
                mrow[ti][r] = mnew;
                float rs = 0.f;
#pragma unroll
                for (int tj = 0; tj < 8; tj++) {
                    float p = exp2f(s[ti][tj][r] - mnew);
                    s[ti][tj][r] = p;
                    rs += p;
                }
#pragma unroll
                for (int off = 1; off < 16; off <<= 1) rs += __shfl_xor(rs, off, 64);
                lrow[ti][r] = lrow[ti][r] * alpha + rs;
#pragma unroll
                for (int di = 0; di < 4; di++) o[ti][di][r] *= alpha;
            }
        }
        // P: C-layout -> LDS row-major [32][128] (wave-private)
#pragma unroll
        for (int ti = 0; ti < 2; ti++)
#pragma unroll
            for (int tj = 0; tj < 8; tj++)
#pragma unroll
                for (int r = 0; r < 4; r++)
                    lP[(ti * 16 + lq * 4 + r) * 128 + tj * 16 + lr] =
                        f2bf(s[ti][tj][r]);
        // O += P @ V
#pragma unroll
        for (int jc = 0; jc < 4; jc++) {
            bf16x8 pa0 = *(const bf16x8*)&lP[(lr) * 128 + jc * 32 + lq * 8];
            bf16x8 pa1 = *(const bf16x8*)&lP[(16 + lr) * 128 + jc * 32 + lq * 8];
#pragma unroll
            for (int di = 0; di < 4; di++) {
                bf16x8 vbf = *(const bf16x8*)&lVt[(di * 16 + lr) * 128 + jc * 32 + lq * 8];
                o[0][di] = __builtin_amdgcn_mfma_f32_16x16x32_bf16(pa0, vbf, o[0][di],
                                                                   0, 0, 0);
                o[1][di] = __builtin_amdgcn_mfma_f32_16x16x32_bf16(pa1, vbf, o[1][di],
                                                                   0, 0, 0);
            }
        }
        __syncthreads();
    }
    // normalize + write [B,S,D] bf16
    int b = bh >> 4, h = bh & 15;
#pragma unroll
    for (int ti = 0; ti < 2; ti++) {
#pragma unroll
        for (int r = 0; r < 4; r++) {
            float inv = 1.0f / lrow[ti][r];
            int row = q0 + w * 32 + ti * 16 + lq * 4 + r;
            size_t tok = (size_t)(b * SEQ + row);
#pragma unroll
            for (int di = 0; di < 4; di++) {
                int col = h * HD + di * 16 + lr;
                AO[tok * D_MODEL + col] = f2bf(o[ti][di][r] * inv);
            }
        }
    }
}

extern "C" void kernel_launch(void* const* d_in, const int* in_sizes, int n_in,
                              void* d_out, int out_size, void* d_ws, size_t ws_size,
                              hipStream_t stream) {
    const float* x  = (const float*)d_in[0];
    const float* Wq = (const float*)d_in[1];
    const float* bq = (const float*)d_in[2];
    const float* Wk = (const float*)d_in[3];
    const float* bk = (const float*)d_in[4];
    const float* Wv = (const float*)d_in[5];
    const float* bv = (const float*)d_in[6];
    const float* Wo = (const float*)d_in[7];
    const float* bo = (const float*)d_in[8];
    float* out = (float*)d_out;

    char* ws = (char*)d_ws;
    u16* xb  = (u16*)ws;                               //  8 MB: x bf16 [4096][1024]
    u16* wt  = (u16*)(ws + (size_t)8 * 1024 * 1024);   //  8 MB: Wq,Wk,Wv,Wo transposed bf16
    u16* qws = (u16*)(ws + (size_t)16 * 1024 * 1024);  //  8 MB: Q [B,H,S,64] (pre-scaled)
    u16* kws = (u16*)(ws + (size_t)24 * 1024 * 1024);  //  8 MB: K
    u16* vws = (u16*)(ws + (size_t)32 * 1024 * 1024);  //  8 MB: V
    u16* ao  = (u16*)(ws + (size_t)40 * 1024 * 1024);  //  8 MB: attn out bf16 [B,S,D]

    k_convert_x<<<4096, 256, 0, stream>>>(x, xb);
    k_convert_wt<<<dim3(32, 32, 4), 256, 0, stream>>>(Wq, Wk, Wv, Wo, wt);
    k_gemm<<<dim3(8, 32, 3), 256, 0, stream>>>(xb, wt, bq, bk, bv,
                                               qws, kws, vws, nullptr, 0);
    k_attn<<<dim3(16, 32), 256, 0, stream>>>(qws, kws, vws, ao);
    k_gemm<<<dim3(8, 32, 1), 256, 0, stream>>>(ao, wt + (size_t)3 * D_MODEL * D_MODEL,
                                               bo, nullptr, nullptr,
                                               nullptr, nullptr, nullptr, out, 1);
}